// Round 7
// baseline (581.966 us; speedup 1.0000x reference)
//
#include <hip/hip_runtime.h>

#define N_NODES 50000
#define N_EDGES 800000
#define N_GRAPHS 64
#define NEG_SLOPE 0.2f
// 1/sqrt(1 + 1e-5), BN eval-mode scale
#define BN_RSQ 0.9999950000374997f

typedef __bf16 bf16x8 __attribute__((ext_vector_type(8)));
typedef float floatx4 __attribute__((ext_vector_type(4)));

__device__ __forceinline__ float lrelu(float v) { return v > 0.0f ? v : NEG_SLOPE * v; }

// bf16 <-> f32 (round-to-nearest-even)
__device__ __forceinline__ float b2f(unsigned short u) {
    return __uint_as_float(((unsigned int)u) << 16);
}
__device__ __forceinline__ unsigned short f2b(float f) {
    unsigned int u = __float_as_uint(f);
    return (unsigned short)((u + 0x7fffu + ((u >> 16) & 1u)) >> 16);
}
// unpack 2 bf16 from one dword (1 instr each: shl / and)
__device__ __forceinline__ float blo(unsigned int d) { return __uint_as_float(d << 16); }
__device__ __forceinline__ float bhi(unsigned int d) { return __uint_as_float(d & 0xffff0000u); }

// ---------------- CSR build (per call; edge list is restored every call) ----------------
__global__ void k_deg(const int* __restrict__ ei, int* __restrict__ deg) {
    int e = blockIdx.x * blockDim.x + threadIdx.x;
    if (e < N_EDGES) atomicAdd(&deg[ei[N_EDGES + e]], 1);
}

// offsets via wave shuffle-scan + one atomic per wave (segment order arbitrary; CSR only
// needs disjoint ranges). Block 0 also computes graph bounds (batch sorted).
__global__ void k_offs(const int* __restrict__ deg, int* __restrict__ offs,
                       int* __restrict__ total, const int* __restrict__ batch,
                       int* __restrict__ bounds) {
    if (blockIdx.x == 0 && threadIdx.x <= N_GRAPHS) {
        int g = threadIdx.x;
        int lo = 0, hi = N_NODES;
        while (lo < hi) {
            int mid = (lo + hi) >> 1;
            if (batch[mid] < g) lo = mid + 1; else hi = mid;
        }
        bounds[g] = lo;
    }
    int i = blockIdx.x * blockDim.x + threadIdx.x;
    int lane = threadIdx.x & 63;
    int v = (i < N_NODES) ? deg[i] : 0;
    int incl = v;
    for (int o = 1; o < 64; o <<= 1) {
        int t = __shfl_up(incl, o);
        if (lane >= o) incl += t;
    }
    int wtot = __shfl(incl, 63);
    int base = 0;
    if (lane == 0) base = atomicAdd(total, wtot);
    base = __shfl(base, 0);
    if (i < N_NODES) offs[i] = base + incl - v;
}

__global__ void k_fill(const int* __restrict__ ei, const int* __restrict__ offs,
                       int* __restrict__ cur, int* __restrict__ csr_src) {
    int e = blockIdx.x * blockDim.x + threadIdx.x;
    if (e < N_EDGES) {
        int d = ei[N_EDGES + e];
        int pos = offs[d] + atomicAdd(&cur[d], 1);
        csr_src[pos] = ei[e];
    }
}

// ---------------- weight prep (all 4 layers): Wt[n*K+k] = bf16(W[k*N+n]) ----------------
__global__ void k_prepw(const float* __restrict__ W1, const float* __restrict__ W2,
                        const float* __restrict__ W3, const float* __restrict__ W4,
                        unsigned short* __restrict__ Wt1, unsigned short* __restrict__ Wt2,
                        unsigned short* __restrict__ Wt3, unsigned short* __restrict__ Wt4) {
    int i = blockIdx.x * blockDim.x + threadIdx.x;
    if (i < 32768) {  // W1: 128x256
        int k = i >> 8, n = i & 255;
        Wt1[n * 128 + k] = f2b(W1[i]);
    } else if (i < 49152) {  // W2: 256x64
        int j = i - 32768;
        int k = j >> 6, n = j & 63;
        Wt2[n * 256 + k] = f2b(W2[j]);
    } else if (i < 53248) {  // W3: 64x64
        int j = i - 49152;
        int k = j >> 6, n = j & 63;
        Wt3[n * 64 + k] = f2b(W3[j]);
    } else if (i < 57344) {  // W4: 64x64
        int j = i - 53248;
        int k = j >> 6, n = j & 63;
        Wt4[n * 64 + k] = f2b(W4[j]);
    }
}

// ---------------- MFMA GEMM + fused attention dots ----------------
// out_bf16[rows,N] = A[rows,K] @ Wt^T; es/ed[row][h] = dot(xW_row_head, a_src/a_dst[h])
// from fp32 accumulators. C/D layout (m89-verified): row=quad*4+rg, col=ct*16+l16.
template <int K, int N, int HEADS, bool AF32>
__global__ __launch_bounds__(256) void k_mgemm(const void* __restrict__ Ap,
                                               const unsigned short* __restrict__ Bt,
                                               const float* __restrict__ asrc,
                                               const float* __restrict__ adst,
                                               unsigned short* __restrict__ out,
                                               float* __restrict__ es,
                                               float* __restrict__ ed, int rows) {
    constexpr int LDP = K + 8;  // bf16 elems; rows stay 16B-aligned, conflicts <=2-way (free)
    __shared__ unsigned short As[64 * LDP];
    const int tid = threadIdx.x;
    const int r0 = blockIdx.x * 64;
    if (AF32) {
        const float* A = (const float*)Ap;
        for (int i = tid; i < 16 * K; i += 256) {
            int r = i / (K / 4), c4 = i % (K / 4);
            int row = r0 + r;
            float4 v = (row < rows) ? *(const float4*)&A[(size_t)row * K + c4 * 4]
                                    : make_float4(0.f, 0.f, 0.f, 0.f);
            ushort4 u;
            u.x = f2b(v.x); u.y = f2b(v.y); u.z = f2b(v.z); u.w = f2b(v.w);
            *(ushort4*)&As[r * LDP + c4 * 4] = u;
        }
    } else {
        const unsigned short* A = (const unsigned short*)Ap;
        for (int i = tid; i < 8 * K; i += 256) {
            int r = i / (K / 8), c8 = i % (K / 8);
            int row = r0 + r;
            uint4 v;
            if (row < rows) v = *(const uint4*)&A[(size_t)row * K + c8 * 8];
            else { v.x = v.y = v.z = v.w = 0; }
            *(uint4*)&As[r * LDP + c8 * 8] = v;
        }
    }
    __syncthreads();
    const int w = tid >> 6, lane = tid & 63;
    const int quad = lane >> 4, l16 = lane & 15;
    const int gr0 = r0 + w * 16 + quad * 4;
    bf16x8 afrag[K / 32];
#pragma unroll
    for (int kk = 0; kk < K / 32; ++kk)
        afrag[kk] = *(const bf16x8*)&As[(w * 16 + l16) * LDP + kk * 32 + quad * 8];
    float sacc[4] = {0.f, 0.f, 0.f, 0.f};
    float dacc[4] = {0.f, 0.f, 0.f, 0.f};
#pragma unroll 1
    for (int ct = 0; ct < N / 16; ++ct) {
        floatx4 acc = {0.f, 0.f, 0.f, 0.f};
#pragma unroll
        for (int kk = 0; kk < K / 32; ++kk) {
            const bf16x8 bfrag =
                *(const bf16x8*)&Bt[(size_t)(ct * 16 + l16) * K + kk * 32 + quad * 8];
            acc = __builtin_amdgcn_mfma_f32_16x16x32_bf16(afrag[kk], bfrag, acc, 0, 0, 0);
        }
        const int gc = ct * 16 + l16;
        const int hh = gc >> 6;  // head = gc/64 (0 when HEADS==1)
        const int f = gc & 63;
        const float as = asrc[hh * 64 + f];
        const float ad = adst[hh * 64 + f];
#pragma unroll
        for (int rg = 0; rg < 4; ++rg) {
            sacc[rg] = fmaf(acc[rg], as, sacc[rg]);
            dacc[rg] = fmaf(acc[rg], ad, dacc[rg]);
        }
#pragma unroll
        for (int rg = 0; rg < 4; ++rg) {
            int gr = gr0 + rg;
            if (gr < rows) out[(size_t)gr * N + gc] = f2b(acc[rg]);
        }
        // head boundary every 64 cols (4 ct tiles): reduce over 16 l16 lanes, store
        if ((ct & 3) == 3) {
#pragma unroll
            for (int rg = 0; rg < 4; ++rg) {
                float s = sacc[rg], d = dacc[rg];
                for (int o = 1; o < 16; o <<= 1) {
                    s += __shfl_xor(s, o);
                    d += __shfl_xor(d, o);
                }
                if (l16 == 0) {
                    int gr = gr0 + rg;
                    if (gr < rows) {
                        es[(size_t)gr * HEADS + hh] = s;
                        ed[(size_t)gr * HEADS + hh] = d;
                    }
                }
                sacc[rg] = 0.f;
                dacc[rg] = 0.f;
            }
        }
    }
}

// ---------------- GAT layer 1: H=4, F=64, out 256 (bf16), + bias + relu ----------------
// TWO waves per dst node; wave owns 128 cols (half = wv&1 -> heads 2h,2h+1).
// Lane: grp=lane>>4 (4 groups), t=lane&15 covers 8 cols at half*128+t*8.
// Inner loop: 16 edges/iter, 4 independent uint4 gathers in flight per lane.
// ps zero-padded past dg; padded gathers hit row 0 (L1-hot). No max-subtraction
// (scores O(1); softmax shift-invariant).
__global__ __launch_bounds__(256) void k_gat1(
    const unsigned short* __restrict__ xW, const float* __restrict__ es, const float* __restrict__ ed,
    const int* __restrict__ offs, const int* __restrict__ deg, const int* __restrict__ csr,
    const float* __restrict__ bias, unsigned short* __restrict__ out) {
    __shared__ float ps[4][128];
    __shared__ int sbuf[4][64];
    const int wv = threadIdx.x >> 6;
    const int lane = threadIdx.x & 63;
    const int n = blockIdx.x * 2 + (wv >> 1);
    const int half = wv & 1;
    if (n >= N_NODES) return;
    const int off = offs[n];
    const int dg = deg[n];
    const float2 edv = *(const float2*)&ed[n * 4 + half * 2];
    const int t = lane & 15, grp = lane >> 4;
    const int hsel = t >> 3;  // which of this wave's 2 heads my cols belong to

    float acc[8];
#pragma unroll
    for (int k = 0; k < 8; ++k) acc[k] = 0.f;
    float dA = 0.f, dB = 0.f;

    for (int base = 0; base < dg; base += 64) {
        const int idx = base + lane;
        int s_l = 0;
        float pA = 0.f, pB = 0.f;
        if (idx < dg) {
            s_l = csr[off + idx];
            const float2 ev = *(const float2*)&es[s_l * 4 + half * 2];
            pA = __expf(lrelu(ev.x + edv.x));
            pB = __expf(lrelu(ev.y + edv.y));
        }
        dA += pA; dB += pB;
        *(float2*)&ps[wv][lane * 2] = make_float2(pA, pB);
        sbuf[wv][lane] = s_l;
        const int cnt = min(64, dg - base);
        const int cntR = (cnt + 15) & ~15;
        for (int j0 = 0; j0 < cntR; j0 += 16) {
            const int j = j0 + grp;
            const float p0 = ps[wv][j * 2 + hsel];
            const float p1 = ps[wv][(j + 4) * 2 + hsel];
            const float p2 = ps[wv][(j + 8) * 2 + hsel];
            const float p3 = ps[wv][(j + 12) * 2 + hsel];
            const int s0 = sbuf[wv][j];
            const int s1 = sbuf[wv][j + 4];
            const int s2 = sbuf[wv][j + 8];
            const int s3 = sbuf[wv][j + 12];
            const int c0 = half * 128 + t * 8;
            const uint4 a0 = *(const uint4*)&xW[(size_t)s0 * 256 + c0];
            const uint4 a1 = *(const uint4*)&xW[(size_t)s1 * 256 + c0];
            const uint4 a2 = *(const uint4*)&xW[(size_t)s2 * 256 + c0];
            const uint4 a3 = *(const uint4*)&xW[(size_t)s3 * 256 + c0];
            acc[0] = fmaf(p0, blo(a0.x), acc[0]);
            acc[1] = fmaf(p0, bhi(a0.x), acc[1]);
            acc[2] = fmaf(p0, blo(a0.y), acc[2]);
            acc[3] = fmaf(p0, bhi(a0.y), acc[3]);
            acc[4] = fmaf(p0, blo(a0.z), acc[4]);
            acc[5] = fmaf(p0, bhi(a0.z), acc[5]);
            acc[6] = fmaf(p0, blo(a0.w), acc[6]);
            acc[7] = fmaf(p0, bhi(a0.w), acc[7]);
            acc[0] = fmaf(p1, blo(a1.x), acc[0]);
            acc[1] = fmaf(p1, bhi(a1.x), acc[1]);
            acc[2] = fmaf(p1, blo(a1.y), acc[2]);
            acc[3] = fmaf(p1, bhi(a1.y), acc[3]);
            acc[4] = fmaf(p1, blo(a1.z), acc[4]);
            acc[5] = fmaf(p1, bhi(a1.z), acc[5]);
            acc[6] = fmaf(p1, blo(a1.w), acc[6]);
            acc[7] = fmaf(p1, bhi(a1.w), acc[7]);
            acc[0] = fmaf(p2, blo(a2.x), acc[0]);
            acc[1] = fmaf(p2, bhi(a2.x), acc[1]);
            acc[2] = fmaf(p2, blo(a2.y), acc[2]);
            acc[3] = fmaf(p2, bhi(a2.y), acc[3]);
            acc[4] = fmaf(p2, blo(a2.z), acc[4]);
            acc[5] = fmaf(p2, bhi(a2.z), acc[5]);
            acc[6] = fmaf(p2, blo(a2.w), acc[6]);
            acc[7] = fmaf(p2, bhi(a2.w), acc[7]);
            acc[0] = fmaf(p3, blo(a3.x), acc[0]);
            acc[1] = fmaf(p3, bhi(a3.x), acc[1]);
            acc[2] = fmaf(p3, blo(a3.y), acc[2]);
            acc[3] = fmaf(p3, bhi(a3.y), acc[3]);
            acc[4] = fmaf(p3, blo(a3.z), acc[4]);
            acc[5] = fmaf(p3, bhi(a3.z), acc[5]);
            acc[6] = fmaf(p3, blo(a3.w), acc[6]);
            acc[7] = fmaf(p3, bhi(a3.w), acc[7]);
        }
    }
    // combine the 4 groups (lanes grp*16+t share cols)
#pragma unroll
    for (int k = 0; k < 8; ++k) {
        acc[k] += __shfl_xor(acc[k], 16);
        acc[k] += __shfl_xor(acc[k], 32);
    }
    for (int o = 1; o < 64; o <<= 1) {
        dA += __shfl_xor(dA, o);
        dB += __shfl_xor(dB, o);
    }
    if (grp == 0) {
        const float dsel = hsel == 0 ? dA : dB;
        const float inv = 1.0f / fmaxf(dsel, 1e-16f);
        const int c0 = half * 128 + t * 8;
        const float4 bv0 = *(const float4*)&bias[c0];
        const float4 bv1 = *(const float4*)&bias[c0 + 4];
        ushort4 o0, o1;
        o0.x = f2b(fmaxf(fmaf(acc[0], inv, bv0.x), 0.f));
        o0.y = f2b(fmaxf(fmaf(acc[1], inv, bv0.y), 0.f));
        o0.z = f2b(fmaxf(fmaf(acc[2], inv, bv0.z), 0.f));
        o0.w = f2b(fmaxf(fmaf(acc[3], inv, bv0.w), 0.f));
        o1.x = f2b(fmaxf(fmaf(acc[4], inv, bv1.x), 0.f));
        o1.y = f2b(fmaxf(fmaf(acc[5], inv, bv1.y), 0.f));
        o1.z = f2b(fmaxf(fmaf(acc[6], inv, bv1.z), 0.f));
        o1.w = f2b(fmaxf(fmaf(acc[7], inv, bv1.w), 0.f));
        *(ushort4*)&out[(size_t)n * 256 + c0] = o0;
        *(ushort4*)&out[(size_t)n * 256 + c0 + 4] = o1;
    }
}

// ---------------- GAT layers 2-4: H=1, F=64, + bias + BN + relu (+ residual) ----------------
// TWO waves per node; wave owns 32 cols. grp=lane>>3 (8 groups/8 edges per iter),
// t=lane&7 covers 4 cols (uint2 gather); unroll x2 -> 16-edge granularity, 2 loads in flight.
template <bool RES>
__global__ __launch_bounds__(256) void k_gatL(
    const unsigned short* __restrict__ xW, const float* __restrict__ es, const float* __restrict__ ed,
    const int* __restrict__ offs, const int* __restrict__ deg, const int* __restrict__ csr,
    const float* __restrict__ bias, const float* __restrict__ gam, const float* __restrict__ bet,
    float* __restrict__ h, unsigned short* __restrict__ hb) {
    __shared__ float ps[4][64];
    __shared__ int sbuf[4][64];
    const int wv = threadIdx.x >> 6;
    const int lane = threadIdx.x & 63;
    const int n = blockIdx.x * 2 + (wv >> 1);
    const int half = wv & 1;
    if (n >= N_NODES) return;
    const int off = offs[n];
    const int dg = deg[n];
    const float edn = ed[n];
    const int t = lane & 7, grp = lane >> 3;

    float acc[4];
#pragma unroll
    for (int k = 0; k < 4; ++k) acc[k] = 0.f;
    float dsum = 0.f;

    for (int base = 0; base < dg; base += 64) {
        const int idx = base + lane;
        int s_l = 0;
        float p_l = 0.f;
        if (idx < dg) {
            s_l = csr[off + idx];
            p_l = __expf(lrelu(es[s_l] + edn));
        }
        dsum += p_l;
        ps[wv][lane] = p_l;
        sbuf[wv][lane] = s_l;
        const int cnt = min(64, dg - base);
        const int cntR = (cnt + 15) & ~15;
        for (int j0 = 0; j0 < cntR; j0 += 16) {
            const int ja = j0 + grp;
            const int jb = ja + 8;
            const float pa = ps[wv][ja];
            const float pb = ps[wv][jb];
            const int sa = sbuf[wv][ja];
            const int sb = sbuf[wv][jb];
            const int c0 = half * 32 + t * 4;
            const uint2 a = *(const uint2*)&xW[(size_t)sa * 64 + c0];
            const uint2 b = *(const uint2*)&xW[(size_t)sb * 64 + c0];
            acc[0] = fmaf(pa, blo(a.x), acc[0]);
            acc[1] = fmaf(pa, bhi(a.x), acc[1]);
            acc[2] = fmaf(pa, blo(a.y), acc[2]);
            acc[3] = fmaf(pa, bhi(a.y), acc[3]);
            acc[0] = fmaf(pb, blo(b.x), acc[0]);
            acc[1] = fmaf(pb, bhi(b.x), acc[1]);
            acc[2] = fmaf(pb, blo(b.y), acc[2]);
            acc[3] = fmaf(pb, bhi(b.y), acc[3]);
        }
    }
#pragma unroll
    for (int k = 0; k < 4; ++k) {
        acc[k] += __shfl_xor(acc[k], 8);
        acc[k] += __shfl_xor(acc[k], 16);
        acc[k] += __shfl_xor(acc[k], 32);
    }
    for (int o = 1; o < 64; o <<= 1) dsum += __shfl_xor(dsum, o);

    if (grp == 0) {
        const float inv = 1.0f / fmaxf(dsum, 1e-16f);
        const int c0 = half * 32 + t * 4;
        float hn[4];
#pragma unroll
        for (int k = 0; k < 4; ++k) {
            const int c = c0 + k;
            const float y = fmaf(acc[k], inv, bias[c]);
            const float z = fmaxf(fmaf(gam[c] * y, BN_RSQ, bet[c]), 0.f);
            hn[k] = RES ? h[(size_t)n * 64 + c] + z : z;
        }
        *(float4*)&h[(size_t)n * 64 + c0] = make_float4(hn[0], hn[1], hn[2], hn[3]);
        ushort4 u;
        u.x = f2b(hn[0]); u.y = f2b(hn[1]); u.z = f2b(hn[2]); u.w = f2b(hn[3]);
        *(ushort4*)&hb[(size_t)n * 64 + c0] = u;
    }
}

// ---------------- mean pool: one block per graph, contiguous node range, no atomics ----------------
__global__ __launch_bounds__(256) void k_pool2(const float* __restrict__ h,
                                               const int* __restrict__ bounds,
                                               float* __restrict__ hp) {
    __shared__ float part[4][64];
    const int g = blockIdx.x;
    const int lane = threadIdx.x & 63;
    const int wid = threadIdx.x >> 6;
    const int s = bounds[g], e = bounds[g + 1];
    float acc = 0.f;
    for (int n = s + wid; n < e; n += 4) acc += h[n * 64 + lane];
    part[wid][lane] = acc;
    __syncthreads();
    if (wid == 0) {
        float v = part[0][lane] + part[1][lane] + part[2][lane] + part[3][lane];
        hp[g * 64 + lane] = v / fmaxf((float)(e - s), 1.0f);
    }
}

// ---------------- MLP head, single block (hp already mean-pooled) ----------------
__global__ __launch_bounds__(256) void k_head(const float* __restrict__ hpg,
                                              const float* __restrict__ Wh1,
                                              const float* __restrict__ bh1,
                                              const float* __restrict__ Wh2,
                                              const float* __restrict__ bh2,
                                              float* __restrict__ out) {
    __shared__ float hp[64 * 64];
    __shared__ float t1[64 * 128];
    const int tid = threadIdx.x;
    for (int i = tid; i < 64 * 64; i += 256) hp[i] = hpg[i];
    __syncthreads();
    for (int i = tid; i < 64 * 128; i += 256) {
        int g = i >> 7, j = i & 127;
        float s = bh1[j];
        for (int k = 0; k < 64; ++k) s = fmaf(hp[g * 64 + k], Wh1[k * 128 + j], s);
        t1[i] = fmaxf(s, 0.f);
    }
    __syncthreads();
    for (int i = tid; i < 640; i += 256) {
        int g = i / 10, j = i - g * 10;
        float s = bh2[j];
        for (int k = 0; k < 128; ++k) s = fmaf(t1[g * 128 + k], Wh2[k * 10 + j], s);
        out[i] = s;
    }
}

extern "C" void kernel_launch(void* const* d_in, const int* in_sizes, int n_in,
                              void* d_out, int out_size, void* d_ws, size_t ws_size,
                              hipStream_t stream) {
    const float* x = (const float*)d_in[1];
    const int* ei = (const int*)d_in[2];
    const int* batch = (const int*)d_in[3];
    const float* W1 = (const float*)d_in[4];
    const float* a_src1 = (const float*)d_in[5];
    const float* a_dst1 = (const float*)d_in[6];
    const float* b1 = (const float*)d_in[7];
    const float* W2 = (const float*)d_in[8];
    const float* a_src2 = (const float*)d_in[9];
    const float* a_dst2 = (const float*)d_in[10];
    const float* b2 = (const float*)d_in[11];
    const float* g2 = (const float*)d_in[12];
    const float* be2 = (const float*)d_in[13];
    const float* W3 = (const float*)d_in[14];
    const float* a_src3 = (const float*)d_in[15];
    const float* a_dst3 = (const float*)d_in[16];
    const float* b3 = (const float*)d_in[17];
    const float* g3 = (const float*)d_in[18];
    const float* be3 = (const float*)d_in[19];
    const float* W4 = (const float*)d_in[20];
    const float* a_src4 = (const float*)d_in[21];
    const float* a_dst4 = (const float*)d_in[22];
    const float* b4 = (const float*)d_in[23];
    const float* g4 = (const float*)d_in[24];
    const float* be4 = (const float*)d_in[25];
    const float* Wh1 = (const float*)d_in[26];
    const float* bh1 = (const float*)d_in[27];
    const float* Wh2 = (const float*)d_in[28];
    const float* bh2 = (const float*)d_in[29];
    float* out = (float*)d_out;

    // workspace layout
    char* p = (char*)d_ws;
    auto alloc = [&](size_t bytes) {
        void* r = (void*)p;
        p += (bytes + 255) & ~(size_t)255;
        return r;
    };
    unsigned short* bufA = (unsigned short*)alloc((size_t)N_NODES * 256 * 2);  // xW bf16 per layer
    unsigned short* x1b = (unsigned short*)alloc((size_t)N_NODES * 256 * 2);   // x1 bf16
    float* h = (float*)alloc((size_t)N_NODES * 64 * 4);                        // h fp32
    unsigned short* hb = (unsigned short*)alloc((size_t)N_NODES * 64 * 2);     // h bf16
    float* es1 = (float*)alloc((size_t)N_NODES * 4 * 4);
    float* ed1 = (float*)alloc((size_t)N_NODES * 4 * 4);
    float* esL = (float*)alloc((size_t)N_NODES * 4);
    float* edL = (float*)alloc((size_t)N_NODES * 4);
    int* offs = (int*)alloc((size_t)N_NODES * 4);
    int* csr = (int*)alloc((size_t)N_EDGES * 4);
    int* bounds = (int*)alloc((size_t)(N_GRAPHS + 1) * 4);
    float* hpool = (float*)alloc((size_t)N_GRAPHS * 64 * 4);
    unsigned short* Wt1 = (unsigned short*)alloc((size_t)128 * 256 * 2);
    unsigned short* Wt2 = (unsigned short*)alloc((size_t)256 * 64 * 2);
    unsigned short* Wt3 = (unsigned short*)alloc((size_t)64 * 64 * 2);
    unsigned short* Wt4 = (unsigned short*)alloc((size_t)64 * 64 * 2);
    char* z0 = p;  // everything below gets zeroed each call
    int* deg = (int*)alloc((size_t)N_NODES * 4);
    int* cur = (int*)alloc((size_t)N_NODES * 4);
    int* total = (int*)alloc(256);
    size_t zbytes = (size_t)(p - z0);
    hipMemsetAsync(z0, 0, zbytes, stream);

    const int edgeBlocks = (N_EDGES + 255) / 256;
    const int nodeBlocks = (N_NODES + 255) / 256;
    const int mgemmBlocks = (N_NODES + 63) / 64;
    const int gatBlocks = (N_NODES + 1) / 2;  // 2 nodes/block, 2 waves/node

    // weight prep (bf16 transpose, all layers)
    k_prepw<<<(57344 + 255) / 256, 256, 0, stream>>>(W1, W2, W3, W4, Wt1, Wt2, Wt3, Wt4);

    // CSR build + graph bounds
    k_deg<<<edgeBlocks, 256, 0, stream>>>(ei, deg);
    k_offs<<<nodeBlocks, 256, 0, stream>>>(deg, offs, total, batch, bounds);
    k_fill<<<edgeBlocks, 256, 0, stream>>>(ei, offs, cur, csr);

    // layer 1: GAT(128 -> 4x64, concat) + relu  (dots fused into GEMM epilogue)
    k_mgemm<128, 256, 4, true><<<mgemmBlocks, 256, 0, stream>>>(x, Wt1, a_src1, a_dst1,
                                                                bufA, es1, ed1, N_NODES);
    k_gat1<<<gatBlocks, 256, 0, stream>>>(bufA, es1, ed1, offs, deg, csr, b1, x1b);

    // layer 2: GAT(256 -> 64) + BN + relu
    k_mgemm<256, 64, 1, false><<<mgemmBlocks, 256, 0, stream>>>(x1b, Wt2, a_src2, a_dst2,
                                                                bufA, esL, edL, N_NODES);
    k_gatL<false><<<gatBlocks, 256, 0, stream>>>(bufA, esL, edL, offs, deg, csr, b2, g2, be2, h, hb);

    // layer 3: residual GAT(64 -> 64) + BN + relu
    k_mgemm<64, 64, 1, false><<<mgemmBlocks, 256, 0, stream>>>(hb, Wt3, a_src3, a_dst3,
                                                               bufA, esL, edL, N_NODES);
    k_gatL<true><<<gatBlocks, 256, 0, stream>>>(bufA, esL, edL, offs, deg, csr, b3, g3, be3, h, hb);

    // layer 4: residual GAT(64 -> 64) + BN + relu
    k_mgemm<64, 64, 1, false><<<mgemmBlocks, 256, 0, stream>>>(hb, Wt4, a_src4, a_dst4,
                                                               bufA, esL, edL, N_NODES);
    k_gatL<true><<<gatBlocks, 256, 0, stream>>>(bufA, esL, edL, offs, deg, csr, b4, g4, be4, h, hb);

    // pool + head (batch sorted -> contiguous ranges, no atomics)
    k_pool2<<<N_GRAPHS, 256, 0, stream>>>(h, bounds, hpool);
    k_head<<<1, 256, 0, stream>>>(hpool, Wh1, bh1, Wh2, bh2, out);
}